// Round 1
// baseline (3889.780 us; speedup 1.0000x reference)
//
#include <hip/hip_runtime.h>
#include <math.h>

#define B 32
#define S 256
#define H 768
#define V 30522
#define NU 5
#define MV 4
#define NEG_INF -10000.0f

__device__ __forceinline__ float sigm(float x){ return 1.0f/(1.0f + expf(-x)); }

// ---------------- GRU: h_new = GRUCell(w, h) fused (gates + combine) -----------
// wave per (j in [0,H), bgroup of 8 batches). 768*4 = 3072 waves, 768 blocks.
__global__ __launch_bounds__(256) void gru_kernel(
    const float* __restrict__ wp, int wstride,
    const float* __restrict__ hin, float* __restrict__ hout,
    const float* __restrict__ Wih, const float* __restrict__ Whh,
    const float* __restrict__ bih, const float* __restrict__ bhh)
{
    int wid  = blockIdx.x * 4 + (threadIdx.x >> 6);
    int lane = threadIdx.x & 63;
    int j  = wid >> 2;     // [0,768)
    int bg = wid & 3;      // [0,4)  -> batches bg*8 .. bg*8+7

    float aI0[8], aI1[8], aI2[8], aH0[8], aH1[8], aH2[8];
#pragma unroll
    for (int bb = 0; bb < 8; bb++){ aI0[bb]=aI1[bb]=aI2[bb]=aH0[bb]=aH1[bb]=aH2[bb]=0.f; }

#pragma unroll
    for (int it = 0; it < 3; it++){
        int k = it*256 + lane*4;
        float4 w0 = *(const float4*)(Wih + (size_t)(0*H + j)*H + k);
        float4 w1 = *(const float4*)(Wih + (size_t)(1*H + j)*H + k);
        float4 w2 = *(const float4*)(Wih + (size_t)(2*H + j)*H + k);
        float4 u0 = *(const float4*)(Whh + (size_t)(0*H + j)*H + k);
        float4 u1 = *(const float4*)(Whh + (size_t)(1*H + j)*H + k);
        float4 u2 = *(const float4*)(Whh + (size_t)(2*H + j)*H + k);
#pragma unroll
        for (int bb = 0; bb < 8; bb++){
            int b = bg*8 + bb;
            float4 x = *(const float4*)(wp  + (size_t)b*wstride + k);
            float4 h = *(const float4*)(hin + (size_t)b*H + k);
            aI0[bb] += w0.x*x.x + w0.y*x.y + w0.z*x.z + w0.w*x.w;
            aI1[bb] += w1.x*x.x + w1.y*x.y + w1.z*x.z + w1.w*x.w;
            aI2[bb] += w2.x*x.x + w2.y*x.y + w2.z*x.z + w2.w*x.w;
            aH0[bb] += u0.x*h.x + u0.y*h.y + u0.z*h.z + u0.w*h.w;
            aH1[bb] += u1.x*h.x + u1.y*h.y + u1.z*h.z + u1.w*h.w;
            aH2[bb] += u2.x*h.x + u2.y*h.y + u2.z*h.z + u2.w*h.w;
        }
    }
    // r and z only need (i+h) sums; n needs i_n and h_n separately -> 32 reductions
    float rRZ0[8], rRZ1[8], rIN[8], rHN[8];
#pragma unroll
    for (int bb = 0; bb < 8; bb++){
        rRZ0[bb] = aI0[bb] + aH0[bb];
        rRZ1[bb] = aI1[bb] + aH1[bb];
        rIN[bb]  = aI2[bb];
        rHN[bb]  = aH2[bb];
    }
#pragma unroll
    for (int bb = 0; bb < 8; bb++){
#pragma unroll
        for (int m = 32; m >= 1; m >>= 1){
            rRZ0[bb] += __shfl_xor(rRZ0[bb], m, 64);
            rRZ1[bb] += __shfl_xor(rRZ1[bb], m, 64);
            rIN[bb]  += __shfl_xor(rIN[bb],  m, 64);
            rHN[bb]  += __shfl_xor(rHN[bb],  m, 64);
        }
    }
    if (lane == 0){
        float brz0 = bih[j]     + bhh[j];
        float brz1 = bih[H+j]   + bhh[H+j];
        float bin_ = bih[2*H+j];
        float bhn_ = bhh[2*H+j];
#pragma unroll
        for (int bb = 0; bb < 8; bb++){
            int b = bg*8 + bb;
            float r = sigm(rRZ0[bb] + brz0);
            float z = sigm(rRZ1[bb] + brz1);
            float n = tanhf(rIN[bb] + bin_ + r*(rHN[bb] + bhn_));
            float ho = hin[(size_t)b*H + j];
            hout[(size_t)b*H + j] = (1.0f - z)*n + z*ho;
        }
    }
}

// ---------------- attn_e[b,s] = enc[b,s,:] . h[b,:] ----------------------------
__global__ __launch_bounds__(256) void attn_e_kernel(
    const float* __restrict__ hb, const float* __restrict__ enc,
    float* __restrict__ attnE)
{
    int wid  = blockIdx.x * 4 + (threadIdx.x >> 6);
    int lane = threadIdx.x & 63;
    int b = wid >> 8;      // wid/256
    int s = wid & 255;
    const float* er = enc + ((size_t)b*S + s)*H;
    const float* hr = hb + (size_t)b*H;
    float acc = 0.f;
#pragma unroll
    for (int it = 0; it < 3; it++){
        int k = it*256 + lane*4;
        float4 e4 = *(const float4*)(er + k);
        float4 h4 = *(const float4*)(hr + k);
        acc += e4.x*h4.x + e4.y*h4.y + e4.z*h4.z + e4.w*h4.w;
    }
#pragma unroll
    for (int m = 32; m >= 1; m >>= 1) acc += __shfl_xor(acc, m, 64);
    if (lane == 0) attnE[b*S + s] = acc;
}

// ------- masked softmax over S (redundant per k-chunk) + context chunk ---------
// grid: 96 blocks = (b, kc in [0,3)) ; 256 threads
__global__ __launch_bounds__(256) void ctx_kernel(
    const float* __restrict__ attnE, const int* __restrict__ ids,
    const float* __restrict__ enc, float* __restrict__ attnH,
    float* __restrict__ ctx)
{
    __shared__ float ah[S];
    __shared__ float red[S];
    int b  = blockIdx.x / 3;
    int kc = blockIdx.x % 3;
    int t  = threadIdx.x;

    float e = attnE[b*S + t];
    if (ids[b*S + t] == 0) e = NEG_INF;
    red[t] = e; __syncthreads();
    for (int s = 128; s > 0; s >>= 1){ if (t < s) red[t] = fmaxf(red[t], red[t+s]); __syncthreads(); }
    float mx = red[0]; __syncthreads();
    float p = expf(e - mx);
    red[t] = p; __syncthreads();
    for (int s = 128; s > 0; s >>= 1){ if (t < s) red[t] += red[t+s]; __syncthreads(); }
    float a = p / red[0];
    ah[t] = a;
    if (kc == 0) attnH[b*S + t] = a;
    __syncthreads();

    int k = kc*256 + t;
    const float* ep = enc + (size_t)b*S*H + k;
    float acc = 0.f;
#pragma unroll 4
    for (int s = 0; s < S; s++) acc += ah[s] * ep[(size_t)s*H];
    ctx[b*H + k] = acc;
}

// ---------------- logits[b,v] = h[b,:] . E[v,:]  (+ pgen in last block) --------
// 239 blocks x 1024 threads cover v; block 239 computes p_gen.
#define LK 384
#define HSTRIDE 388   // 388 % 32 == 4 -> only 4-way LDS bank aliasing
__global__ __launch_bounds__(1024) void logits_kernel(
    const float* __restrict__ hb, const float* __restrict__ E,
    float* __restrict__ logits,
    const float* __restrict__ wp, int wstride,
    const float* __restrict__ ctx, const float* __restrict__ wgw,
    const float* __restrict__ wgb, float* __restrict__ pgen)
{
    __shared__ float sh[32 * HSTRIDE];
    int t = threadIdx.x;

    if (blockIdx.x == 239){
        int b = t >> 5, sl = t & 31;
        float s = 0.f;
        for (int i = sl; i < 2304; i += 32){
            float xv;
            if (i < 768)        xv = wp[(size_t)b*wstride + i];
            else if (i < 1536)  xv = hb[b*H + (i - 768)];
            else                xv = ctx[b*H + (i - 1536)];
            s += xv * wgw[i];
        }
#pragma unroll
        for (int m = 16; m >= 1; m >>= 1) s += __shfl_xor(s, m, 32);
        if (sl == 0) pgen[b] = sigm(s + wgb[0]);
        return;
    }

    int lane = t & 63;
    int w    = t >> 6;
    int b    = lane & 31;
    int vh   = lane >> 5;
    int v0   = blockIdx.x*128 + w*8 + vh*4;

    float acc0 = 0.f, acc1 = 0.f, acc2 = 0.f, acc3 = 0.f;

    for (int ph = 0; ph < 2; ph++){
        __syncthreads();
        for (int i = t; i < 32*LK; i += 1024){
            int bb = i / LK; int c = i - bb*LK;
            sh[bb*HSTRIDE + c] = hb[bb*H + ph*LK + c];
        }
        __syncthreads();
        const float* hrow = sh + b*HSTRIDE;
        if (v0 + 3 < V){
            const float* e0 = E + (size_t)(v0+0)*H + ph*LK;
            const float* e1 = E + (size_t)(v0+1)*H + ph*LK;
            const float* e2 = E + (size_t)(v0+2)*H + ph*LK;
            const float* e3 = E + (size_t)(v0+3)*H + ph*LK;
            for (int k = 0; k < LK; k += 4){
                float4 h4 = *(const float4*)(hrow + k);
                float4 a4 = *(const float4*)(e0 + k);
                float4 b4 = *(const float4*)(e1 + k);
                float4 c4 = *(const float4*)(e2 + k);
                float4 d4 = *(const float4*)(e3 + k);
                acc0 += h4.x*a4.x + h4.y*a4.y + h4.z*a4.z + h4.w*a4.w;
                acc1 += h4.x*b4.x + h4.y*b4.y + h4.z*b4.z + h4.w*b4.w;
                acc2 += h4.x*c4.x + h4.y*c4.y + h4.z*c4.z + h4.w*c4.w;
                acc3 += h4.x*d4.x + h4.y*d4.y + h4.z*d4.z + h4.w*d4.w;
            }
        } else {
#pragma unroll
            for (int jj = 0; jj < 4; jj++){
                int v = v0 + jj;
                if (v < V){
                    const float* ev = E + (size_t)v*H + ph*LK;
                    float a = 0.f;
                    for (int k = 0; k < LK; k += 4){
                        float4 h4 = *(const float4*)(hrow + k);
                        float4 e4 = *(const float4*)(ev + k);
                        a += h4.x*e4.x + h4.y*e4.y + h4.z*e4.z + h4.w*e4.w;
                    }
                    if (jj == 0) acc0 += a; else if (jj == 1) acc1 += a;
                    else if (jj == 2) acc2 += a; else acc3 += a;
                }
            }
        }
    }
    if (v0 + 0 < V) logits[(size_t)b*V + v0 + 0] = acc0;
    if (v0 + 1 < V) logits[(size_t)b*V + v0 + 1] = acc1;
    if (v0 + 2 < V) logits[(size_t)b*V + v0 + 2] = acc2;
    if (v0 + 3 < V) logits[(size_t)b*V + v0 + 3] = acc3;
}

// ---------------- per-b max and sum(exp(l-max)) over V -------------------------
__global__ __launch_bounds__(1024) void vred_kernel(
    const float* __restrict__ logits, float* __restrict__ vmax, float* __restrict__ vsum)
{
    __shared__ float red[1024];
    int b = blockIdx.x, t = threadIdx.x;
    float r[30]; int n = 0;
    float mx = -INFINITY;
    for (int i = t; i < V; i += 1024){
        float x = logits[(size_t)b*V + i];
        r[n++] = x;
        mx = fmaxf(mx, x);
    }
    red[t] = mx; __syncthreads();
    for (int s = 512; s > 0; s >>= 1){ if (t < s) red[t] = fmaxf(red[t], red[t+s]); __syncthreads(); }
    mx = red[0]; __syncthreads();
    float sm = 0.f;
    for (int i = 0; i < n; i++) sm += expf(r[i] - mx);
    red[t] = sm; __syncthreads();
    for (int s = 512; s > 0; s >>= 1){ if (t < s) red[t] += red[t+s]; __syncthreads(); }
    if (t == 0){ vmax[b] = mx; vsum[b] = red[0]; }
}

// ---------------- out = p_gen * softmax(logits) --------------------------------
__global__ __launch_bounds__(1024) void final_kernel(
    const float* __restrict__ logits, const float* __restrict__ vmax,
    const float* __restrict__ vsum, const float* __restrict__ pgen,
    float* __restrict__ out, int u, int mm)
{
    int b = blockIdx.y;
    int v = blockIdx.x*1024 + threadIdx.x;
    if (v >= V) return;
    float val = pgen[b] * expf(logits[(size_t)b*V + v] - vmax[b]) / vsum[b];
    out[(((size_t)b*NU + u)*MV + mm)*(size_t)V + v] = val;
}

// ---------------- pointer scatter: out[b,u,m,ids[b,s]] += (1-pg)*ah[b,s] -------
__global__ __launch_bounds__(256) void scatter_kernel(
    const float* __restrict__ attnH, const int* __restrict__ ids,
    const float* __restrict__ pgen, float* __restrict__ out, int u, int mm)
{
    int b = blockIdx.x, s = threadIdx.x;
    int id = ids[b*S + s];
    float val = (1.0f - pgen[b]) * attnH[b*S + s];
    atomicAdd(out + (((size_t)b*NU + u)*MV + mm)*(size_t)V + id, val);
}

// ---------------- argmax over p_final row (numpy first-index) + gather w -------
__global__ __launch_bounds__(1024) void argmax_kernel(
    const float* __restrict__ out, int u, int mm,
    const float* __restrict__ E, float* __restrict__ wbuf)
{
    __shared__ float rv[1024];
    __shared__ int   ri[1024];
    int b = blockIdx.x, t = threadIdx.x;
    const float* row = out + (((size_t)b*NU + u)*MV + mm)*(size_t)V;
    float bv = -INFINITY; int bi = 0;
    for (int i = t; i < V; i += 1024){
        float x = row[i];
        if (x > bv){ bv = x; bi = i; }
    }
    rv[t] = bv; ri[t] = bi; __syncthreads();
    for (int s = 512; s > 0; s >>= 1){
        if (t < s){
            if (rv[t+s] > rv[t] || (rv[t+s] == rv[t] && ri[t+s] < ri[t])){
                rv[t] = rv[t+s]; ri[t] = ri[t+s];
            }
        }
        __syncthreads();
    }
    int idx = ri[0];
    for (int k = t; k < H; k += 1024) wbuf[b*H + k] = E[(size_t)idx*H + k];
}

extern "C" void kernel_launch(void* const* d_in, const int* in_sizes, int n_in,
                              void* d_out, int out_size, void* d_ws, size_t ws_size,
                              hipStream_t stream)
{
    const int*   ids = (const int*)  d_in[0];
    const float* dec = (const float*)d_in[1];
    const float* enc = (const float*)d_in[2];
    const float* hid = (const float*)d_in[3];
    const float* E   = (const float*)d_in[4];
    const float* Wih = (const float*)d_in[5];
    const float* Whh = (const float*)d_in[6];
    const float* bih = (const float*)d_in[7];
    const float* bhh = (const float*)d_in[8];
    const float* wgw = (const float*)d_in[9];
    const float* wgb = (const float*)d_in[10];
    float* out = (float*)d_out;
    float* ws  = (float*)d_ws;

    float* wbuf    = ws;                 // 24576
    float* hb0     = ws + 24576;         // 24576
    float* hb1     = ws + 49152;         // 24576
    float* ctxb    = ws + 73728;         // 24576
    float* attnE   = ws + 98304;         // 8192
    float* attnH   = ws + 106496;        // 8192
    float* logitsb = ws + 114688;        // 976704
    float* pgenb   = ws + 1091392;       // 32
    float* vmaxb   = ws + 1091424;       // 32
    float* vsumb   = ws + 1091456;       // 32

    for (int u = 0; u < NU; u++){
        for (int mm = 0; mm < MV; mm++){
            int st = u*MV + mm;
            const float* wp; int wstride;
            if (mm == 0){ wp = dec + (size_t)u*H; wstride = NU*H; }
            else        { wp = wbuf;              wstride = H; }
            const float* hin = (st == 0) ? hid : ((st & 1) ? hb0 : hb1);
            float*      hout = (st & 1) ? hb1 : hb0;

            gru_kernel<<<768, 256, 0, stream>>>(wp, wstride, hin, hout, Wih, Whh, bih, bhh);
            attn_e_kernel<<<2048, 256, 0, stream>>>(hout, enc, attnE);
            ctx_kernel<<<96, 256, 0, stream>>>(attnE, ids, enc, attnH, ctxb);
            logits_kernel<<<240, 1024, 0, stream>>>(hout, E, logitsb, wp, wstride, ctxb, wgw, wgb, pgenb);
            vred_kernel<<<32, 1024, 0, stream>>>(logitsb, vmaxb, vsumb);
            final_kernel<<<dim3(30, 32), 1024, 0, stream>>>(logitsb, vmaxb, vsumb, pgenb, out, u, mm);
            scatter_kernel<<<32, 256, 0, stream>>>(attnH, ids, pgenb, out, u, mm);
            if (mm != MV-1)
                argmax_kernel<<<32, 1024, 0, stream>>>(out, u, mm, E, wbuf);
        }
    }
}

// Round 2
// 3417.280 us; speedup vs baseline: 1.1383x; 1.1383x over previous
//
#include <hip/hip_runtime.h>
#include <math.h>

#define B 32
#define S 256
#define H 768
#define V 30522
#define NU 5
#define MV 4
#define NEG_INF -10000.0f

// logits GEMM tiling
#define VP 30720      // padded V (120 tiles * 256)
#define KSPLIT 4
#define KCH 192       // 768 / KSPLIT
#define KT 32         // k-phase staged in LDS
#define VT 256        // v per block
#define VPAD 260      // LDS row stride

__device__ __forceinline__ float sigm(float x){ return 1.0f/(1.0f + expf(-x)); }

// ---------------- GRU: h_new = GRUCell(w, h), writes h and h-transposed --------
__global__ __launch_bounds__(256) void gru_kernel(
    const float* __restrict__ wp, int wstride,
    const float* __restrict__ hin, float* __restrict__ hout,
    float* __restrict__ htr,
    const float* __restrict__ Wih, const float* __restrict__ Whh,
    const float* __restrict__ bih, const float* __restrict__ bhh)
{
    int wid  = blockIdx.x * 4 + (threadIdx.x >> 6);
    int lane = threadIdx.x & 63;
    int j  = wid >> 2;     // [0,768)
    int bg = wid & 3;      // [0,4)  -> batches bg*8 .. bg*8+7

    float aI0[8], aI1[8], aI2[8], aH0[8], aH1[8], aH2[8];
#pragma unroll
    for (int bb = 0; bb < 8; bb++){ aI0[bb]=aI1[bb]=aI2[bb]=aH0[bb]=aH1[bb]=aH2[bb]=0.f; }

#pragma unroll
    for (int it = 0; it < 3; it++){
        int k = it*256 + lane*4;
        float4 w0 = *(const float4*)(Wih + (size_t)(0*H + j)*H + k);
        float4 w1 = *(const float4*)(Wih + (size_t)(1*H + j)*H + k);
        float4 w2 = *(const float4*)(Wih + (size_t)(2*H + j)*H + k);
        float4 u0 = *(const float4*)(Whh + (size_t)(0*H + j)*H + k);
        float4 u1 = *(const float4*)(Whh + (size_t)(1*H + j)*H + k);
        float4 u2 = *(const float4*)(Whh + (size_t)(2*H + j)*H + k);
#pragma unroll
        for (int bb = 0; bb < 8; bb++){
            int b = bg*8 + bb;
            float4 x = *(const float4*)(wp  + (size_t)b*wstride + k);
            float4 h = *(const float4*)(hin + (size_t)b*H + k);
            aI0[bb] += w0.x*x.x + w0.y*x.y + w0.z*x.z + w0.w*x.w;
            aI1[bb] += w1.x*x.x + w1.y*x.y + w1.z*x.z + w1.w*x.w;
            aI2[bb] += w2.x*x.x + w2.y*x.y + w2.z*x.z + w2.w*x.w;
            aH0[bb] += u0.x*h.x + u0.y*h.y + u0.z*h.z + u0.w*h.w;
            aH1[bb] += u1.x*h.x + u1.y*h.y + u1.z*h.z + u1.w*h.w;
            aH2[bb] += u2.x*h.x + u2.y*h.y + u2.z*h.z + u2.w*h.w;
        }
    }
    float rRZ0[8], rRZ1[8], rIN[8], rHN[8];
#pragma unroll
    for (int bb = 0; bb < 8; bb++){
        rRZ0[bb] = aI0[bb] + aH0[bb];
        rRZ1[bb] = aI1[bb] + aH1[bb];
        rIN[bb]  = aI2[bb];
        rHN[bb]  = aH2[bb];
    }
#pragma unroll
    for (int bb = 0; bb < 8; bb++){
#pragma unroll
        for (int m = 32; m >= 1; m >>= 1){
            rRZ0[bb] += __shfl_xor(rRZ0[bb], m, 64);
            rRZ1[bb] += __shfl_xor(rRZ1[bb], m, 64);
            rIN[bb]  += __shfl_xor(rIN[bb],  m, 64);
            rHN[bb]  += __shfl_xor(rHN[bb],  m, 64);
        }
    }
    if (lane == 0){
        float brz0 = bih[j]     + bhh[j];
        float brz1 = bih[H+j]   + bhh[H+j];
        float bin_ = bih[2*H+j];
        float bhn_ = bhh[2*H+j];
#pragma unroll
        for (int bb = 0; bb < 8; bb++){
            int b = bg*8 + bb;
            float r = sigm(rRZ0[bb] + brz0);
            float z = sigm(rRZ1[bb] + brz1);
            float n = tanhf(rIN[bb] + bin_ + r*(rHN[bb] + bhn_));
            float ho = hin[(size_t)b*H + j];
            float hv = (1.0f - z)*n + z*ho;
            hout[(size_t)b*H + j] = hv;
            htr[(size_t)j*32 + b] = hv;   // transposed copy for SGPR h-loads
        }
    }
}

// ---------------- attn_e[b,s] = enc[b,s,:] . h[b,:] ----------------------------
__global__ __launch_bounds__(256) void attn_e_kernel(
    const float* __restrict__ hb, const float* __restrict__ enc,
    float* __restrict__ attnE)
{
    int wid  = blockIdx.x * 4 + (threadIdx.x >> 6);
    int lane = threadIdx.x & 63;
    int b = wid >> 8;
    int s = wid & 255;
    const float* er = enc + ((size_t)b*S + s)*H;
    const float* hr = hb + (size_t)b*H;
    float acc = 0.f;
#pragma unroll
    for (int it = 0; it < 3; it++){
        int k = it*256 + lane*4;
        float4 e4 = *(const float4*)(er + k);
        float4 h4 = *(const float4*)(hr + k);
        acc += e4.x*h4.x + e4.y*h4.y + e4.z*h4.z + e4.w*h4.w;
    }
#pragma unroll
    for (int m = 32; m >= 1; m >>= 1) acc += __shfl_xor(acc, m, 64);
    if (lane == 0) attnE[b*S + s] = acc;
}

// ------- masked softmax over S (redundant per k-chunk) + context chunk ---------
__global__ __launch_bounds__(256) void ctx_kernel(
    const float* __restrict__ attnE, const int* __restrict__ ids,
    const float* __restrict__ enc, float* __restrict__ attnH,
    float* __restrict__ ctx)
{
    __shared__ float ah[S];
    __shared__ float red[S];
    int b  = blockIdx.x / 3;
    int kc = blockIdx.x % 3;
    int t  = threadIdx.x;

    float e = attnE[b*S + t];
    if (ids[b*S + t] == 0) e = NEG_INF;
    red[t] = e; __syncthreads();
    for (int s = 128; s > 0; s >>= 1){ if (t < s) red[t] = fmaxf(red[t], red[t+s]); __syncthreads(); }
    float mx = red[0]; __syncthreads();
    float p = expf(e - mx);
    red[t] = p; __syncthreads();
    for (int s = 128; s > 0; s >>= 1){ if (t < s) red[t] += red[t+s]; __syncthreads(); }
    float a = p / red[0];
    ah[t] = a;
    if (kc == 0) attnH[b*S + t] = a;
    __syncthreads();

    int k = kc*256 + t;
    const float* ep = enc + (size_t)b*S*H + k;
    float acc = 0.f;
#pragma unroll 4
    for (int s = 0; s < S; s++) acc += ah[s] * ep[(size_t)s*H];
    ctx[b*H + k] = acc;
}

// ---------------- logits partial GEMM: 256v x 32b tile, K/4 per block ----------
// grid 481 blocks: [0,480) = (vtile*4 + ksplit); block 480 = p_gen.
__global__ __launch_bounds__(256) void logits_kernel(
    const float* __restrict__ E, const float* __restrict__ htr,
    float* __restrict__ part,
    const float* __restrict__ hb, const float* __restrict__ wp, int wstride,
    const float* __restrict__ ctx, const float* __restrict__ wgw,
    const float* __restrict__ wgb, float* __restrict__ pgen)
{
    int t = threadIdx.x;

    if (blockIdx.x == 480){
        int b = t >> 3, sl = t & 7;
        float s = 0.f;
        for (int i = sl; i < 2304; i += 8){
            float xv;
            if (i < 768)        xv = wp[(size_t)b*wstride + i];
            else if (i < 1536)  xv = hb[b*H + (i - 768)];
            else                xv = ctx[b*H + (i - 1536)];
            s += xv * wgw[i];
        }
#pragma unroll
        for (int m = 4; m >= 1; m >>= 1) s += __shfl_xor(s, m, 8);
        if (sl == 0) pgen[b] = sigm(s + wgb[0]);
        return;
    }

    __shared__ float Ets[KT][VPAD];
    int vt = blockIdx.x >> 2;
    int ks = blockIdx.x & 3;
    int v0 = vt * VT;
    int k0 = ks * KCH;

    int wu = __builtin_amdgcn_readfirstlane(t >> 6); // wave id -> b base 8*wu
    int l  = t & 63;                                  // lane -> 4 v's at v0+4l
    int r  = t >> 3;                                  // staging row
    int c4 = t & 7;                                   // staging col-quad

    float4 acc[8];
#pragma unroll
    for (int j = 0; j < 8; j++){ acc[j].x=0.f; acc[j].y=0.f; acc[j].z=0.f; acc[j].w=0.f; }

    for (int ph = 0; ph < KCH/KT; ph++){
        int kb = k0 + ph*KT;
        __syncthreads();
#pragma unroll
        for (int p = 0; p < 8; p++){
            int vv = v0 + p*32 + r;
            int vr = vv < V ? vv : V-1;               // clamp OOB rows (unused values)
            float4 e4 = *(const float4*)(E + (size_t)vr*H + kb + c4*4);
            int vloc = p*32 + r;
            Ets[c4*4+0][vloc] = e4.x;
            Ets[c4*4+1][vloc] = e4.y;
            Ets[c4*4+2][vloc] = e4.z;
            Ets[c4*4+3][vloc] = e4.w;
        }
        __syncthreads();
        const float* hkp = htr + (size_t)kb*32 + 8*wu;
#pragma unroll
        for (int k = 0; k < KT; k++){
            float4 e4 = *(const float4*)(&Ets[k][l*4]);
            float h0 = hkp[k*32+0], h1 = hkp[k*32+1], h2 = hkp[k*32+2], h3 = hkp[k*32+3];
            float h4 = hkp[k*32+4], h5 = hkp[k*32+5], h6 = hkp[k*32+6], h7 = hkp[k*32+7];
            acc[0].x += h0*e4.x; acc[0].y += h0*e4.y; acc[0].z += h0*e4.z; acc[0].w += h0*e4.w;
            acc[1].x += h1*e4.x; acc[1].y += h1*e4.y; acc[1].z += h1*e4.z; acc[1].w += h1*e4.w;
            acc[2].x += h2*e4.x; acc[2].y += h2*e4.y; acc[2].z += h2*e4.z; acc[2].w += h2*e4.w;
            acc[3].x += h3*e4.x; acc[3].y += h3*e4.y; acc[3].z += h3*e4.z; acc[3].w += h3*e4.w;
            acc[4].x += h4*e4.x; acc[4].y += h4*e4.y; acc[4].z += h4*e4.z; acc[4].w += h4*e4.w;
            acc[5].x += h5*e4.x; acc[5].y += h5*e4.y; acc[5].z += h5*e4.z; acc[5].w += h5*e4.w;
            acc[6].x += h6*e4.x; acc[6].y += h6*e4.y; acc[6].z += h6*e4.z; acc[6].w += h6*e4.w;
            acc[7].x += h7*e4.x; acc[7].y += h7*e4.y; acc[7].z += h7*e4.z; acc[7].w += h7*e4.w;
        }
    }
    float* pp = part + (size_t)ks*32*VP;
    int v = v0 + l*4;
#pragma unroll
    for (int j = 0; j < 8; j++){
        int b = 8*wu + j;
        *(float4*)(pp + (size_t)b*VP + v) = acc[j];
    }
}

// ---------------- per-b max and sum(exp(l-max)) over V (4 partials) ------------
__global__ __launch_bounds__(1024) void vred_kernel(
    const float* __restrict__ part, float* __restrict__ vmax, float* __restrict__ vsum)
{
    __shared__ float red[1024];
    int b = blockIdx.x, t = threadIdx.x;
    float r[30]; int n = 0;
    float mx = -INFINITY;
    for (int i = t; i < V; i += 1024){
        float x = part[(size_t)b*VP + i]
                + part[(size_t)(32+b)*VP + i]
                + part[(size_t)(64+b)*VP + i]
                + part[(size_t)(96+b)*VP + i];
        r[n++] = x;
        mx = fmaxf(mx, x);
    }
    red[t] = mx; __syncthreads();
    for (int s = 512; s > 0; s >>= 1){ if (t < s) red[t] = fmaxf(red[t], red[t+s]); __syncthreads(); }
    mx = red[0]; __syncthreads();
    float sm = 0.f;
    for (int i = 0; i < n; i++) sm += expf(r[i] - mx);
    red[t] = sm; __syncthreads();
    for (int s = 512; s > 0; s >>= 1){ if (t < s) red[t] += red[t+s]; __syncthreads(); }
    if (t == 0){ vmax[b] = mx; vsum[b] = red[0]; }
}

// ---------------- out = p_gen * softmax(logits) --------------------------------
__global__ __launch_bounds__(1024) void final_kernel(
    const float* __restrict__ part, const float* __restrict__ vmax,
    const float* __restrict__ vsum, const float* __restrict__ pgen,
    float* __restrict__ out, int u, int mm)
{
    int b = blockIdx.y;
    int v = blockIdx.x*1024 + threadIdx.x;
    if (v >= V) return;
    float x = part[(size_t)b*VP + v]
            + part[(size_t)(32+b)*VP + v]
            + part[(size_t)(64+b)*VP + v]
            + part[(size_t)(96+b)*VP + v];
    float val = pgen[b] * expf(x - vmax[b]) / vsum[b];
    out[(((size_t)b*NU + u)*MV + mm)*(size_t)V + v] = val;
}

// ---------------- pointer scatter ----------------------------------------------
__global__ __launch_bounds__(256) void scatter_kernel(
    const float* __restrict__ attnH, const int* __restrict__ ids,
    const float* __restrict__ pgen, float* __restrict__ out, int u, int mm)
{
    int b = blockIdx.x, s = threadIdx.x;
    int id = ids[b*S + s];
    float val = (1.0f - pgen[b]) * attnH[b*S + s];
    atomicAdd(out + (((size_t)b*NU + u)*MV + mm)*(size_t)V + id, val);
}

// ---------------- argmax (numpy first-index) + gather next w -------------------
__global__ __launch_bounds__(1024) void argmax_kernel(
    const float* __restrict__ out, int u, int mm,
    const float* __restrict__ E, float* __restrict__ wbuf)
{
    __shared__ float rv[1024];
    __shared__ int   ri[1024];
    int b = blockIdx.x, t = threadIdx.x;
    const float* row = out + (((size_t)b*NU + u)*MV + mm)*(size_t)V;
    float bv = -INFINITY; int bi = 0;
    for (int i = t; i < V; i += 1024){
        float x = row[i];
        if (x > bv){ bv = x; bi = i; }
    }
    rv[t] = bv; ri[t] = bi; __syncthreads();
    for (int s = 512; s > 0; s >>= 1){
        if (t < s){
            if (rv[t+s] > rv[t] || (rv[t+s] == rv[t] && ri[t+s] < ri[t])){
                rv[t] = rv[t+s]; ri[t] = ri[t+s];
            }
        }
        __syncthreads();
    }
    int idx = ri[0];
    for (int k = t; k < H; k += 1024) wbuf[b*H + k] = E[(size_t)idx*H + k];
}

extern "C" void kernel_launch(void* const* d_in, const int* in_sizes, int n_in,
                              void* d_out, int out_size, void* d_ws, size_t ws_size,
                              hipStream_t stream)
{
    const int*   ids = (const int*)  d_in[0];
    const float* dec = (const float*)d_in[1];
    const float* enc = (const float*)d_in[2];
    const float* hid = (const float*)d_in[3];
    const float* E   = (const float*)d_in[4];
    const float* Wih = (const float*)d_in[5];
    const float* Whh = (const float*)d_in[6];
    const float* bih = (const float*)d_in[7];
    const float* bhh = (const float*)d_in[8];
    const float* wgw = (const float*)d_in[9];
    const float* wgb = (const float*)d_in[10];
    float* out = (float*)d_out;
    float* ws  = (float*)d_ws;

    float* wbuf    = ws;                 // 24576
    float* hb0     = ws + 24576;         // 24576
    float* hb1     = ws + 49152;         // 24576
    float* ctxb    = ws + 73728;         // 24576
    float* attnE   = ws + 98304;         // 8192
    float* attnH   = ws + 106496;        // 8192
    float* htr     = ws + 114688;        // 24576 (h transposed [768][32])
    float* pgenb   = ws + 139264;        // 32
    float* vmaxb   = ws + 139296;        // 32
    float* vsumb   = ws + 139328;        // 32
    float* part    = ws + 139360;        // 4*32*30720 = 3,932,160

    for (int u = 0; u < NU; u++){
        for (int mm = 0; mm < MV; mm++){
            int st = u*MV + mm;
            const float* wp; int wstride;
            if (mm == 0){ wp = dec + (size_t)u*H; wstride = NU*H; }
            else        { wp = wbuf;              wstride = H; }
            const float* hin = (st == 0) ? hid : ((st & 1) ? hb0 : hb1);
            float*      hout = (st & 1) ? hb1 : hb0;

            gru_kernel<<<768, 256, 0, stream>>>(wp, wstride, hin, hout, htr, Wih, Whh, bih, bhh);
            attn_e_kernel<<<2048, 256, 0, stream>>>(hout, enc, attnE);
            ctx_kernel<<<96, 256, 0, stream>>>(attnE, ids, enc, attnH, ctxb);
            logits_kernel<<<481, 256, 0, stream>>>(E, htr, part, hout, wp, wstride, ctxb, wgw, wgb, pgenb);
            vred_kernel<<<32, 1024, 0, stream>>>(part, vmaxb, vsumb);
            final_kernel<<<dim3(30, 32), 1024, 0, stream>>>(part, vmaxb, vsumb, pgenb, out, u, mm);
            scatter_kernel<<<32, 256, 0, stream>>>(attnH, ids, pgenb, out, u, mm);
            if (mm != MV-1)
                argmax_kernel<<<32, 1024, 0, stream>>>(out, u, mm, E, wbuf);
        }
    }
}